// Round 8
// baseline (286.616 us; speedup 1.0000x reference)
//
#include <hip/hip_runtime.h>
#include <math.h>

#define NEG 0.2f
#define LNEPS 1e-5f

typedef __attribute__((ext_vector_type(8))) short bf16x8;
typedef __attribute__((ext_vector_type(8))) unsigned short u16x8;
typedef __attribute__((ext_vector_type(4))) float f32x4;

__device__ __forceinline__ float lrelu(float x){ return x > 0.f ? x : NEG*x; }

__device__ __forceinline__ short f2b(float f){
  unsigned u = __float_as_uint(f);
  unsigned r = u + 0x7fffu + ((u >> 16) & 1u);
  return (short)(r >> 16);
}
__device__ __forceinline__ float b2f(unsigned short u){
  return __uint_as_float(((unsigned)u) << 16);
}

// -------- W transpose + bf16 convert, plus WS = bf16(W @ [att_src|att_dst]) ----
// blocks 0..255: WT[c][k] = bf16(W[k][c]).  blocks 256..271: WS[col][k].
__global__ __launch_bounds__(256) void wt_k(const float* __restrict__ W,
                                            const float* __restrict__ att_src,
                                            const float* __restrict__ att_dst,
                                            unsigned short* __restrict__ WT,
                                            unsigned short* __restrict__ WS){
  int b = blockIdx.x;
  if (b < 256){
    int idx = b*256 + threadIdx.x;
    int k = idx >> 8, c = idx & 255;
    WT[c*256 + k] = (unsigned short)f2b(W[idx]);
  } else {
    int idx = (b-256)*256 + threadIdx.x;   // 0..4095
    int col = idx >> 8;                    // 0..15 (0-7 src, 8-15 dst)
    int k   = idx & 255;
    int head = col & 7;
    const float* av = (col < 8 ? att_src : att_dst) + head*32;
    const float* wr = W + (size_t)k*256 + head*32;
    float sum = 0.f;
    #pragma unroll
    for (int c=0;c<32;c++) sum += wr[c]*av[c];
    WS[col*256 + k] = (unsigned short)f2b(sum);
  }
}

// -------- MFMA GEMM, B-in-registers; att logits as 16 extra cols (wave 0) ----
__device__ __forceinline__ void load_half(float4 nx[8], const float* p){
  #pragma unroll
  for (int s=0;s<4;s++){
    nx[2*s]   = *(const float4*)(p + s*32);
    nx[2*s+1] = *(const float4*)(p + s*32 + 4);
  }
}
__device__ __forceinline__ void cvt_half(bf16x8 af[4], const float4 nx[8]){
  #pragma unroll
  for (int s=0;s<4;s++){
    af[s][0]=f2b(nx[2*s].x);   af[s][1]=f2b(nx[2*s].y);
    af[s][2]=f2b(nx[2*s].z);   af[s][3]=f2b(nx[2*s].w);
    af[s][4]=f2b(nx[2*s+1].x); af[s][5]=f2b(nx[2*s+1].y);
    af[s][6]=f2b(nx[2*s+1].z); af[s][7]=f2b(nx[2*s+1].w);
  }
}

__global__ __launch_bounds__(256, 4) void mfma_gemm_k(const float* __restrict__ A,
    const unsigned short* __restrict__ WT, const unsigned short* __restrict__ WS,
    unsigned short* __restrict__ Cb,
    float* __restrict__ a_src, float* __restrict__ a_dst, int M, int nTiles){
  int w   = threadIdx.x >> 6;
  int l   = threadIdx.x & 63;
  int l15 = l & 15;
  int kg  = l >> 4;
  int colbase = w*64;

  bf16x8 bfr[4][8];
  #pragma unroll
  for (int j=0;j<4;j++){
    const unsigned short* bp = WT + (size_t)(colbase + j*16 + l15)*256 + kg*8;
    #pragma unroll
    for (int ks=0;ks<8;ks++) bfr[j][ks] = *(const bf16x8*)(bp + ks*32);
  }
  // att B-fragments (wave 0 only reads; uniform branch)
  bf16x8 bfa[8];
  if (w==0){
    const unsigned short* bp = WS + (size_t)l15*256 + kg*8;
    #pragma unroll
    for (int ks=0;ks<8;ks++) bfa[ks] = *(const bf16x8*)(bp + ks*32);
  }

  int t = blockIdx.x;
  if (t >= nTiles) return;
  int row0 = t*16 + l15;
  const float* ap = A + (size_t)(row0 < M ? row0 : M-1)*256 + kg*8;
  float4 nx[8];
  load_half(nx, ap);

  while (t < nTiles){
    f32x4 acc[4];
    #pragma unroll
    for (int j=0;j<4;j++) acc[j] = (f32x4){0.f,0.f,0.f,0.f};
    f32x4 acc_a = (f32x4){0.f,0.f,0.f,0.f};
    bf16x8 af[4];

    cvt_half(af, nx);
    load_half(nx, ap + 128);
    #pragma unroll
    for (int s=0;s<4;s++){
      #pragma unroll
      for (int j=0;j<4;j++)
        acc[j] = __builtin_amdgcn_mfma_f32_16x16x32_bf16(af[s], bfr[j][s], acc[j], 0, 0, 0);
      if (w==0)
        acc_a = __builtin_amdgcn_mfma_f32_16x16x32_bf16(af[s], bfa[s], acc_a, 0, 0, 0);
    }

    int tn = t + gridDim.x;
    int rown = tn < nTiles ? tn*16 + l15 : row0;
    const float* apn = A + (size_t)(rown < M ? rown : M-1)*256 + kg*8;

    cvt_half(af, nx);
    load_half(nx, apn);
    #pragma unroll
    for (int s=0;s<4;s++){
      #pragma unroll
      for (int j=0;j<4;j++)
        acc[j] = __builtin_amdgcn_mfma_f32_16x16x32_bf16(af[s], bfr[j][4+s], acc[j], 0, 0, 0);
      if (w==0)
        acc_a = __builtin_amdgcn_mfma_f32_16x16x32_bf16(af[s], bfa[4+s], acc_a, 0, 0, 0);
    }

    // D layout: col=l15, row=kg*4+reg
    int orow_base = t*16 + kg*4;
    #pragma unroll
    for (int j=0;j<4;j++)
      #pragma unroll
      for (int rr=0;rr<4;rr++){
        int orow = orow_base + rr;
        if (orow < M) Cb[(size_t)orow*256 + colbase + j*16 + l15] = (unsigned short)f2b(acc[j][rr]);
      }
    if (w==0){
      #pragma unroll
      for (int rr=0;rr<4;rr++){
        int orow = orow_base + rr;
        if (orow < M){
          if (l15 < 8) a_src[(size_t)orow*8 + l15]     = acc_a[rr];
          else         a_dst[(size_t)orow*8 + l15 - 8] = acc_a[rr];
        }
      }
    }
    t = tn; row0 = rown; ap = apn;
  }
}

// -------- CSR build (self-loops folded in: deg starts at 1) --------
__global__ void dinit_k(int* __restrict__ deg, int n){
  int i = blockIdx.x*blockDim.x+threadIdx.x;
  if (i<n) deg[i]=1;
}

__global__ void deg_k(const int* __restrict__ dst, int* __restrict__ deg, int E){
  int e = blockIdx.x*blockDim.x+threadIdx.x;
  if (e<E) atomicAdd(&deg[dst[e]],1);
}

__global__ __launch_bounds__(1024) void scan1_k(const int* __restrict__ deg,
                                                int* __restrict__ off,
                                                int* __restrict__ bsum, int n){
  __shared__ int wsum[16];
  int tid=threadIdx.x, lane=tid&63, wid=tid>>6;
  int i = blockIdx.x*1024 + tid;
  int v = (i<n)?deg[i]:0;
  int x = v;
  #pragma unroll
  for (int s=1;s<64;s<<=1){ int t2=__shfl_up(x,s); if (lane>=s) x+=t2; }
  if (lane==63) wsum[wid]=x;
  __syncthreads();
  if (tid<16){
    int y=wsum[tid];
    #pragma unroll
    for (int s=1;s<16;s<<=1){ int t2=__shfl_up(y,s); if (tid>=s) y+=t2; }
    wsum[tid]=y;
  }
  __syncthreads();
  int prefix=(wid? wsum[wid-1]:0);
  if (i<n) off[i]=prefix + x - v;
  if (tid==0) bsum[blockIdx.x]=wsum[15];
}

__global__ void scan2_k(int* __restrict__ bsum, int nb, int* __restrict__ offn){
  int lane = threadIdx.x;
  int v = (lane<nb)?bsum[lane]:0;
  int x = v;
  #pragma unroll
  for (int s=1;s<64;s<<=1){ int t2=__shfl_up(x,s); if (lane>=s) x+=t2; }
  if (lane<nb) bsum[lane] = x - v;
  if (lane==63) *offn = x;
}

// finalize offsets + plant self edge (slot 0), cur=1
__global__ __launch_bounds__(1024) void scan3self_k(int* __restrict__ off,
    const int* __restrict__ bsum, int* __restrict__ sorted, int* __restrict__ cur, int n){
  int i = blockIdx.x*1024 + threadIdx.x;
  if (i>=n) return;
  int o = off[i] + bsum[blockIdx.x];
  off[i] = o;
  sorted[o] = i;
  cur[i] = 1;
}

__global__ void scatter_k(const int* __restrict__ src, const int* __restrict__ dst,
                          const int* __restrict__ off, int* __restrict__ cur,
                          int* __restrict__ sorted, int E){
  int e=blockIdx.x*blockDim.x+threadIdx.x;
  if (e<E){
    int d=dst[e];
    int pos=off[d]+atomicAdd(&cur[d],1);
    sorted[pos]=src[e];
  }
}

// -------- aggregate + softmax + LayerNorm; distributed-exp weights --------
// Wave = 1 node; halves gather full 512B rows at 16B/lane. Per 8-edge block,
// lane (je=lane>>3, hh=lane&7) computes the ONE exp for (edge je, head hh);
// accumulation lanes fetch their weight via shfl.
__global__ __launch_bounds__(256) void agg5_k(const unsigned short* __restrict__ xlb,
    const float* __restrict__ a_src, const float* __restrict__ a_dst,
    const int* __restrict__ off, const int* __restrict__ sorted,
    const float* __restrict__ bias, const float* __restrict__ gamma,
    const float* __restrict__ beta, float* __restrict__ out, int n){
  int node = blockIdx.x*4 + (threadIdx.x>>6);
  if (node >= n) return;
  int lane = threadIdx.x & 63;
  int half = lane >> 5;
  int sl   = lane & 31;
  int h    = sl >> 2;          // head for accumulation (4 lanes/head)
  int hh   = lane & 7;         // head for exp duty
  int je   = lane >> 3;        // edge slot for exp duty (0..7)
  float adst_h = a_dst[(size_t)node*8 + h];
  float adst_e = a_dst[(size_t)node*8 + hh];
  int s0 = off[node], dd = off[node+1] - s0;   // includes self edge

  float acc[8] = {0.f,0.f,0.f,0.f,0.f,0.f,0.f,0.f};
  float den = 0.f;

  int i = 0;
  for (; i+8 <= dd; i += 8){
    int s[4];
    #pragma unroll
    for (int j=0;j<4;j++) s[j] = sorted[s0 + i + 2*j + half];
    int se = sorted[s0 + i + je];
    float w_l = __expf(lrelu(a_src[(size_t)se*8 + hh] + adst_e));
    float wv[4];
    #pragma unroll
    for (int j=0;j<4;j++) wv[j] = __shfl(w_l, ((2*j+half)<<3) | h);
    u16x8 u[4];
    #pragma unroll
    for (int j=0;j<4;j++) u[j] = *(const u16x8*)(xlb + (size_t)s[j]*256 + sl*8);
    #pragma unroll
    for (int j=0;j<4;j++){
      den += wv[j];
      #pragma unroll
      for (int k=0;k<8;k++) acc[k] += wv[j]*b2f((unsigned short)u[j][k]);
    }
  }
  for (; i < dd; i += 2){
    int idx = i + half;
    bool ok = idx < dd;
    int s1 = ok ? sorted[s0+idx] : node;
    float w1 = ok ? __expf(lrelu(a_src[(size_t)s1*8+h]+adst_h)) : 0.f;
    u16x8 u1 = *(const u16x8*)(xlb + (size_t)s1*256 + sl*8);
    den += w1;
    #pragma unroll
    for (int k=0;k<8;k++) acc[k] += w1*b2f((unsigned short)u1[k]);
  }

  // cross-half merge
  den += __shfl_xor(den, 32);
  #pragma unroll
  for (int k=0;k<8;k++) acc[k] += __shfl_xor(acc[k], 32);

  float rd = 1.0f/den;
  float4 bia0 = *(const float4*)(bias + sl*8);
  float4 bia1 = *(const float4*)(bias + sl*8 + 4);
  float o[8];
  o[0]=acc[0]*rd+bia0.x; o[1]=acc[1]*rd+bia0.y; o[2]=acc[2]*rd+bia0.z; o[3]=acc[3]*rd+bia0.w;
  o[4]=acc[4]*rd+bia1.x; o[5]=acc[5]*rd+bia1.y; o[6]=acc[6]*rd+bia1.z; o[7]=acc[7]*rd+bia1.w;

  float sum=0.f, ssq=0.f;
  #pragma unroll
  for (int k=0;k<8;k++){ sum += o[k]; ssq += o[k]*o[k]; }
  #pragma unroll
  for (int s=1;s<32;s<<=1){ sum += __shfl_xor(sum,s); ssq += __shfl_xor(ssq,s); }
  float mean = sum*(1.0f/256.0f);
  float var  = ssq*(1.0f/256.0f) - mean*mean;
  float rstd = rsqrtf(var + LNEPS);

  int f = sl*8 + half*4;
  float4 g  = *(const float4*)(gamma + f);
  float4 be = *(const float4*)(beta + f);
  int kb = half*4;
  float4 ov;
  ov.x = (o[kb+0]-mean)*rstd*g.x+be.x;
  ov.y = (o[kb+1]-mean)*rstd*g.y+be.y;
  ov.z = (o[kb+2]-mean)*rstd*g.z+be.z;
  ov.w = (o[kb+3]-mean)*rstd*g.w+be.w;
  *(float4*)(out + (size_t)node*256 + f) = ov;
}

extern "C" void kernel_launch(void* const* d_in, const int* in_sizes, int n_in,
                              void* d_out, int out_size, void* d_ws, size_t ws_size,
                              hipStream_t stream){
  const float* x       = (const float*)d_in[0];
  const int*   ei      = (const int*)  d_in[1];
  const float* W       = (const float*)d_in[2];
  const float* att_src = (const float*)d_in[3];
  const float* att_dst = (const float*)d_in[4];
  const float* bias    = (const float*)d_in[5];
  const float* gamma   = (const float*)d_in[6];
  const float* beta    = (const float*)d_in[7];
  float* out = (float*)d_out;

  int N = in_sizes[0]/256;
  int E = in_sizes[1]/2;
  const int* srcp = ei;
  const int* dstp = ei + E;

  unsigned short* xlb = (unsigned short*)d_ws;               // N*256 bf16
  float* a_src = (float*)(xlb + (size_t)N*256);
  float* a_dst = a_src + (size_t)N*8;
  int*   deg   = (int*)(a_dst + (size_t)N*8);
  int*   off   = deg + N;
  int*   cur   = off + N + 1;
  int*   sorted= cur + N;                                    // E+N entries
  int*   bsum  = sorted + E + N;
  unsigned short* WT = (unsigned short*)(bsum + 1024);
  unsigned short* WS = WT + 65536;                           // 16*256 bf16

  int nb = (N + 1023)/1024;
  int nTiles = (N + 15)/16;

  wt_k<<<272, 256, 0, stream>>>(W, att_src, att_dst, WT, WS);
  mfma_gemm_k<<<1024, 256, 0, stream>>>(x, WT, WS, xlb, a_src, a_dst, N, nTiles);
  dinit_k<<<(N+255)/256, 256, 0, stream>>>(deg, N);
  deg_k<<<(E+255)/256, 256, 0, stream>>>(dstp, deg, E);
  scan1_k<<<nb, 1024, 0, stream>>>(deg, off, bsum, N);
  scan2_k<<<1, 64, 0, stream>>>(bsum, nb, off + N);
  scan3self_k<<<nb, 1024, 0, stream>>>(off, bsum, sorted, cur, N);
  scatter_k<<<(E+255)/256, 256, 0, stream>>>(srcp, dstp, off, cur, sorted, E);
  agg5_k<<<(N+3)/4, 256, 0, stream>>>(xlb, a_src, a_dst, off, sorted, bias, gamma, beta, out, N);
}

// Round 9
// 207.625 us; speedup vs baseline: 1.3805x; 1.3805x over previous
//
#include <hip/hip_runtime.h>
#include <math.h>

#define NEG 0.2f
#define LNEPS 1e-5f

typedef __attribute__((ext_vector_type(8))) short bf16x8;
typedef __attribute__((ext_vector_type(8))) unsigned short u16x8;
typedef __attribute__((ext_vector_type(4))) float f32x4;

__device__ __forceinline__ float lrelu(float x){ return x > 0.f ? x : NEG*x; }

__device__ __forceinline__ short f2b(float f){
  unsigned u = __float_as_uint(f);
  unsigned r = u + 0x7fffu + ((u >> 16) & 1u);
  return (short)(r >> 16);
}
__device__ __forceinline__ float b2f(unsigned short u){
  return __uint_as_float(((unsigned)u) << 16);
}

// -------- W transpose + bf16 convert, plus WS = bf16(W @ [att_src|att_dst]) ----
__global__ __launch_bounds__(256) void wt_k(const float* __restrict__ W,
                                            const float* __restrict__ att_src,
                                            const float* __restrict__ att_dst,
                                            unsigned short* __restrict__ WT,
                                            unsigned short* __restrict__ WS){
  int b = blockIdx.x;
  if (b < 256){
    int idx = b*256 + threadIdx.x;
    int k = idx >> 8, c = idx & 255;
    WT[c*256 + k] = (unsigned short)f2b(W[idx]);
  } else {
    int idx = (b-256)*256 + threadIdx.x;   // 0..4095
    int col = idx >> 8;                    // 0..15 (0-7 src, 8-15 dst)
    int k   = idx & 255;
    int head = col & 7;
    const float* av = (col < 8 ? att_src : att_dst) + head*32;
    const float* wr = W + (size_t)k*256 + head*32;
    float sum = 0.f;
    #pragma unroll
    for (int c=0;c<32;c++) sum += wr[c]*av[c];
    WS[col*256 + k] = (unsigned short)f2b(sum);
  }
}

// -------- MFMA GEMM, B-in-registers; att logits as 16 extra cols (wave 0) ----
// launch_bounds(256,2): needs ~200 VGPR; (256,4) caps at 64 and spills (r8 lesson).
__device__ __forceinline__ void load_half(float4 nx[8], const float* p){
  #pragma unroll
  for (int s=0;s<4;s++){
    nx[2*s]   = *(const float4*)(p + s*32);
    nx[2*s+1] = *(const float4*)(p + s*32 + 4);
  }
}
__device__ __forceinline__ void cvt_half(bf16x8 af[4], const float4 nx[8]){
  #pragma unroll
  for (int s=0;s<4;s++){
    af[s][0]=f2b(nx[2*s].x);   af[s][1]=f2b(nx[2*s].y);
    af[s][2]=f2b(nx[2*s].z);   af[s][3]=f2b(nx[2*s].w);
    af[s][4]=f2b(nx[2*s+1].x); af[s][5]=f2b(nx[2*s+1].y);
    af[s][6]=f2b(nx[2*s+1].z); af[s][7]=f2b(nx[2*s+1].w);
  }
}

__global__ __launch_bounds__(256, 2) void mfma_gemm_k(const float* __restrict__ A,
    const unsigned short* __restrict__ WT, const unsigned short* __restrict__ WS,
    unsigned short* __restrict__ Cb,
    float* __restrict__ a_src, float* __restrict__ a_dst, int M, int nTiles){
  int w   = threadIdx.x >> 6;
  int l   = threadIdx.x & 63;
  int l15 = l & 15;
  int kg  = l >> 4;
  int colbase = w*64;

  bf16x8 bfr[4][8];
  #pragma unroll
  for (int j=0;j<4;j++){
    const unsigned short* bp = WT + (size_t)(colbase + j*16 + l15)*256 + kg*8;
    #pragma unroll
    for (int ks=0;ks<8;ks++) bfr[j][ks] = *(const bf16x8*)(bp + ks*32);
  }
  // att B-fragments (wave 0 only; uniform branch)
  bf16x8 bfa[8];
  if (w==0){
    const unsigned short* bp = WS + (size_t)l15*256 + kg*8;
    #pragma unroll
    for (int ks=0;ks<8;ks++) bfa[ks] = *(const bf16x8*)(bp + ks*32);
  }

  int t = blockIdx.x;
  if (t >= nTiles) return;
  int row0 = t*16 + l15;
  const float* ap = A + (size_t)(row0 < M ? row0 : M-1)*256 + kg*8;
  float4 nx[8];
  load_half(nx, ap);

  while (t < nTiles){
    f32x4 acc[4];
    #pragma unroll
    for (int j=0;j<4;j++) acc[j] = (f32x4){0.f,0.f,0.f,0.f};
    f32x4 acc_a = (f32x4){0.f,0.f,0.f,0.f};
    bf16x8 af[4];

    cvt_half(af, nx);
    load_half(nx, ap + 128);
    #pragma unroll
    for (int s=0;s<4;s++){
      #pragma unroll
      for (int j=0;j<4;j++)
        acc[j] = __builtin_amdgcn_mfma_f32_16x16x32_bf16(af[s], bfr[j][s], acc[j], 0, 0, 0);
      if (w==0)
        acc_a = __builtin_amdgcn_mfma_f32_16x16x32_bf16(af[s], bfa[s], acc_a, 0, 0, 0);
    }

    int tn = t + gridDim.x;
    int rown = tn < nTiles ? tn*16 + l15 : row0;
    const float* apn = A + (size_t)(rown < M ? rown : M-1)*256 + kg*8;

    cvt_half(af, nx);
    load_half(nx, apn);
    #pragma unroll
    for (int s=0;s<4;s++){
      #pragma unroll
      for (int j=0;j<4;j++)
        acc[j] = __builtin_amdgcn_mfma_f32_16x16x32_bf16(af[s], bfr[j][4+s], acc[j], 0, 0, 0);
      if (w==0)
        acc_a = __builtin_amdgcn_mfma_f32_16x16x32_bf16(af[s], bfa[4+s], acc_a, 0, 0, 0);
    }

    // D layout: col=l15, row=kg*4+reg
    int orow_base = t*16 + kg*4;
    #pragma unroll
    for (int j=0;j<4;j++)
      #pragma unroll
      for (int rr=0;rr<4;rr++){
        int orow = orow_base + rr;
        if (orow < M) Cb[(size_t)orow*256 + colbase + j*16 + l15] = (unsigned short)f2b(acc[j][rr]);
      }
    if (w==0){
      #pragma unroll
      for (int rr=0;rr<4;rr++){
        int orow = orow_base + rr;
        if (orow < M){
          if (l15 < 8) a_src[(size_t)orow*8 + l15]     = acc_a[rr];
          else         a_dst[(size_t)orow*8 + l15 - 8] = acc_a[rr];
        }
      }
    }
    t = tn; row0 = rown; ap = apn;
  }
}

// -------- CSR build (self-loops folded in: deg starts at 1) --------
__global__ void dinit_k(int* __restrict__ deg, int n){
  int i = blockIdx.x*blockDim.x+threadIdx.x;
  if (i<n) deg[i]=1;
}

__global__ void deg_k(const int* __restrict__ dst, int* __restrict__ deg, int E){
  int e = blockIdx.x*blockDim.x+threadIdx.x;
  if (e<E) atomicAdd(&deg[dst[e]],1);
}

__global__ __launch_bounds__(1024) void scan1_k(const int* __restrict__ deg,
                                                int* __restrict__ off,
                                                int* __restrict__ bsum, int n){
  __shared__ int wsum[16];
  int tid=threadIdx.x, lane=tid&63, wid=tid>>6;
  int i = blockIdx.x*1024 + tid;
  int v = (i<n)?deg[i]:0;
  int x = v;
  #pragma unroll
  for (int s=1;s<64;s<<=1){ int t2=__shfl_up(x,s); if (lane>=s) x+=t2; }
  if (lane==63) wsum[wid]=x;
  __syncthreads();
  if (tid<16){
    int y=wsum[tid];
    #pragma unroll
    for (int s=1;s<16;s<<=1){ int t2=__shfl_up(y,s); if (tid>=s) y+=t2; }
    wsum[tid]=y;
  }
  __syncthreads();
  int prefix=(wid? wsum[wid-1]:0);
  if (i<n) off[i]=prefix + x - v;
  if (tid==0) bsum[blockIdx.x]=wsum[15];
}

__global__ void scan2_k(int* __restrict__ bsum, int nb, int* __restrict__ offn){
  int lane = threadIdx.x;
  int v = (lane<nb)?bsum[lane]:0;
  int x = v;
  #pragma unroll
  for (int s=1;s<64;s<<=1){ int t2=__shfl_up(x,s); if (lane>=s) x+=t2; }
  if (lane<nb) bsum[lane] = x - v;
  if (lane==63) *offn = x;
}

// finalize offsets + plant self edge (slot 0), cur=1
__global__ __launch_bounds__(1024) void scan3self_k(int* __restrict__ off,
    const int* __restrict__ bsum, int* __restrict__ sorted, int* __restrict__ cur, int n){
  int i = blockIdx.x*1024 + threadIdx.x;
  if (i>=n) return;
  int o = off[i] + bsum[blockIdx.x];
  off[i] = o;
  sorted[o] = i;
  cur[i] = 1;
}

__global__ void scatter_k(const int* __restrict__ src, const int* __restrict__ dst,
                          const int* __restrict__ off, int* __restrict__ cur,
                          int* __restrict__ sorted, int E){
  int e=blockIdx.x*blockDim.x+threadIdx.x;
  if (e<E){
    int d=dst[e];
    int pos=off[d]+atomicAdd(&cur[d],1);
    sorted[pos]=src[e];
  }
}

// -------- aggregate + softmax + LayerNorm; distributed-exp weights --------
__global__ __launch_bounds__(256) void agg5_k(const unsigned short* __restrict__ xlb,
    const float* __restrict__ a_src, const float* __restrict__ a_dst,
    const int* __restrict__ off, const int* __restrict__ sorted,
    const float* __restrict__ bias, const float* __restrict__ gamma,
    const float* __restrict__ beta, float* __restrict__ out, int n){
  int node = blockIdx.x*4 + (threadIdx.x>>6);
  if (node >= n) return;
  int lane = threadIdx.x & 63;
  int half = lane >> 5;
  int sl   = lane & 31;
  int h    = sl >> 2;          // head for accumulation (4 lanes/head)
  int hh   = lane & 7;         // head for exp duty
  int je   = lane >> 3;        // edge slot for exp duty (0..7)
  float adst_h = a_dst[(size_t)node*8 + h];
  float adst_e = a_dst[(size_t)node*8 + hh];
  int s0 = off[node], dd = off[node+1] - s0;   // includes self edge

  float acc[8] = {0.f,0.f,0.f,0.f,0.f,0.f,0.f,0.f};
  float den = 0.f;

  int i = 0;
  for (; i+8 <= dd; i += 8){
    int s[4];
    #pragma unroll
    for (int j=0;j<4;j++) s[j] = sorted[s0 + i + 2*j + half];
    int se = sorted[s0 + i + je];
    float w_l = __expf(lrelu(a_src[(size_t)se*8 + hh] + adst_e));
    float wv[4];
    #pragma unroll
    for (int j=0;j<4;j++) wv[j] = __shfl(w_l, ((2*j+half)<<3) | h);
    u16x8 u[4];
    #pragma unroll
    for (int j=0;j<4;j++) u[j] = *(const u16x8*)(xlb + (size_t)s[j]*256 + sl*8);
    #pragma unroll
    for (int j=0;j<4;j++){
      den += wv[j];
      #pragma unroll
      for (int k=0;k<8;k++) acc[k] += wv[j]*b2f((unsigned short)u[j][k]);
    }
  }
  for (; i < dd; i += 2){
    int idx = i + half;
    bool ok = idx < dd;
    int s1 = ok ? sorted[s0+idx] : node;
    float w1 = ok ? __expf(lrelu(a_src[(size_t)s1*8+h]+adst_h)) : 0.f;
    u16x8 u1 = *(const u16x8*)(xlb + (size_t)s1*256 + sl*8);
    den += w1;
    #pragma unroll
    for (int k=0;k<8;k++) acc[k] += w1*b2f((unsigned short)u1[k]);
  }

  // cross-half merge
  den += __shfl_xor(den, 32);
  #pragma unroll
  for (int k=0;k<8;k++) acc[k] += __shfl_xor(acc[k], 32);

  float rd = 1.0f/den;
  float4 bia0 = *(const float4*)(bias + sl*8);
  float4 bia1 = *(const float4*)(bias + sl*8 + 4);
  float o[8];
  o[0]=acc[0]*rd+bia0.x; o[1]=acc[1]*rd+bia0.y; o[2]=acc[2]*rd+bia0.z; o[3]=acc[3]*rd+bia0.w;
  o[4]=acc[4]*rd+bia1.x; o[5]=acc[5]*rd+bia1.y; o[6]=acc[6]*rd+bia1.z; o[7]=acc[7]*rd+bia1.w;

  float sum=0.f, ssq=0.f;
  #pragma unroll
  for (int k=0;k<8;k++){ sum += o[k]; ssq += o[k]*o[k]; }
  #pragma unroll
  for (int s=1;s<32;s<<=1){ sum += __shfl_xor(sum,s); ssq += __shfl_xor(ssq,s); }
  float mean = sum*(1.0f/256.0f);
  float var  = ssq*(1.0f/256.0f) - mean*mean;
  float rstd = rsqrtf(var + LNEPS);

  int f = sl*8 + half*4;
  float4 g  = *(const float4*)(gamma + f);
  float4 be = *(const float4*)(beta + f);
  int kb = half*4;
  float4 ov;
  ov.x = (o[kb+0]-mean)*rstd*g.x+be.x;
  ov.y = (o[kb+1]-mean)*rstd*g.y+be.y;
  ov.z = (o[kb+2]-mean)*rstd*g.z+be.z;
  ov.w = (o[kb+3]-mean)*rstd*g.w+be.w;
  *(float4*)(out + (size_t)node*256 + f) = ov;
}

extern "C" void kernel_launch(void* const* d_in, const int* in_sizes, int n_in,
                              void* d_out, int out_size, void* d_ws, size_t ws_size,
                              hipStream_t stream){
  const float* x       = (const float*)d_in[0];
  const int*   ei      = (const int*)  d_in[1];
  const float* W       = (const float*)d_in[2];
  const float* att_src = (const float*)d_in[3];
  const float* att_dst = (const float*)d_in[4];
  const float* bias    = (const float*)d_in[5];
  const float* gamma   = (const float*)d_in[6];
  const float* beta    = (const float*)d_in[7];
  float* out = (float*)d_out;

  int N = in_sizes[0]/256;
  int E = in_sizes[1]/2;
  const int* srcp = ei;
  const int* dstp = ei + E;

  unsigned short* xlb = (unsigned short*)d_ws;               // N*256 bf16
  float* a_src = (float*)(xlb + (size_t)N*256);
  float* a_dst = a_src + (size_t)N*8;
  int*   deg   = (int*)(a_dst + (size_t)N*8);
  int*   off   = deg + N;
  int*   cur   = off + N + 1;
  int*   sorted= cur + N;                                    // E+N entries
  int*   bsum  = sorted + E + N;
  unsigned short* WT = (unsigned short*)(bsum + 1024);
  unsigned short* WS = WT + 65536;                           // 16*256 bf16

  int nb = (N + 1023)/1024;
  int nTiles = (N + 15)/16;

  wt_k<<<272, 256, 0, stream>>>(W, att_src, att_dst, WT, WS);
  mfma_gemm_k<<<512, 256, 0, stream>>>(x, WT, WS, xlb, a_src, a_dst, N, nTiles);
  dinit_k<<<(N+255)/256, 256, 0, stream>>>(deg, N);
  deg_k<<<(E+255)/256, 256, 0, stream>>>(dstp, deg, E);
  scan1_k<<<nb, 1024, 0, stream>>>(deg, off, bsum, N);
  scan2_k<<<1, 64, 0, stream>>>(bsum, nb, off + N);
  scan3self_k<<<nb, 1024, 0, stream>>>(off, bsum, sorted, cur, N);
  scatter_k<<<(E+255)/256, 256, 0, stream>>>(srcp, dstp, off, cur, sorted, E);
  agg5_k<<<(N+3)/4, 256, 0, stream>>>(xlb, a_src, a_dst, off, sorted, bias, gamma, beta, out, N);
}